// Round 18
// baseline (294.214 us; speedup 1.0000x reference)
//
#include <hip/hip_runtime.h>

#define NPTS 16384
#define GRID 16
#define SGRID 8
#define NCELL 4096          // 16^3
#define CS_STRIDE (NCELL+1)
#define GLO -4.0f
#define GH 0.5f
#define GINVH 2.0f
#define NOCT 8192

// sets: 0 = xyz1[b=0], 1 = xyz1[b=1], 2 = xyz2[b=0], 3 = xyz2[b=1]
// ws layout (bytes):
//   float4 spts[4][NPTS]            @ 0        (1048576)  Morton-sorted; w = __int_as_float(orig idx)
//   int    cellStart[4][NCELL+1]    @ 1048576  (65552)
//   int    hist[4][NCELL]           @ 1114128  (65536)
//   int    cursor[4][NCELL]         @ 1179664  (65536)
//   int    octbkt[NOCT]             @ 1245200  (32768)
//   int    bcnt[32]                 @ 1277968  (128)
//   int    bcur[32]                 @ 1278096  (128)
//   int    perm[NOCT]               @ 1278224  (32768)
// total 1310992 bytes

__device__ __forceinline__ int clamp16(int v){ return v<0?0:(v>15?15:v); }
__device__ __forceinline__ int spr3(int v){           // 4-bit -> bits 0,3,6,9
    return (v&1) | ((v&2)<<2) | ((v&4)<<4) | ((v&8)<<6);
}
__device__ __forceinline__ int mcode(int ix,int iy,int iz){
    return spr3(ix) | (spr3(iy)<<1) | (spr3(iz)<<2);  // 12-bit Morton
}

__global__ __launch_bounds__(256) void zero_hist(int* __restrict__ hist,
                                                 int* __restrict__ bcnt,
                                                 int* __restrict__ bcur){
    hist[blockIdx.x*256 + threadIdx.x] = 0;           // grid 64 -> 16384 ints
    if (blockIdx.x == 0 && threadIdx.x < 32) { bcnt[threadIdx.x] = 0; bcur[threadIdx.x] = 0; }
}

__global__ __launch_bounds__(256) void bin_kernel(
    const float* __restrict__ xyz1, const float* __restrict__ xyz2,
    int* __restrict__ hist)
{
    int t = blockIdx.x*256 + threadIdx.x;             // 0..65535
    int s = t >> 14, i = t & (NPTS-1);
    const float* src = (s < 2 ? xyz1 : xyz2) + ((size_t)(s&1)*NPTS + i)*3;
    float x = src[0], y = src[1], z = src[2];
    int ix = clamp16((int)floorf((x-GLO)*GINVH));
    int iy = clamp16((int)floorf((y-GLO)*GINVH));
    int iz = clamp16((int)floorf((z-GLO)*GINVH));
    atomicAdd(&hist[s*NCELL + mcode(ix,iy,iz)], 1);
}

// one block (1024 thr) per set: exclusive scan of 4096 counts
__global__ __launch_bounds__(1024) void scan_kernel(
    const int* __restrict__ hist, int* __restrict__ cellStart, int* __restrict__ cursor)
{
    int s = blockIdx.x, tid = threadIdx.x, lane = tid & 63, w = tid >> 6; // 16 waves
    const int* h = hist + s*NCELL;
    int v0 = h[tid*4+0], v1 = h[tid*4+1], v2 = h[tid*4+2], v3 = h[tid*4+3];
    int tsum = v0+v1+v2+v3;
    int x = tsum;
    #pragma unroll
    for (int d = 1; d < 64; d <<= 1) { int y = __shfl_up(x, d, 64); if (lane >= d) x += y; }
    __shared__ int wsum[16];
    if (lane == 63) wsum[w] = x;
    __syncthreads();
    if (tid == 0) { int acc = 0; for (int i2 = 0; i2 < 16; ++i2) { int tt = wsum[i2]; wsum[i2] = acc; acc += tt; } }
    __syncthreads();
    int excl = x - tsum + wsum[w];
    int* cs = cellStart + s*CS_STRIDE;
    int* cu = cursor   + s*NCELL;
    cs[tid*4+0] = excl; cu[tid*4+0] = excl; excl += v0;
    cs[tid*4+1] = excl; cu[tid*4+1] = excl; excl += v1;
    cs[tid*4+2] = excl; cu[tid*4+2] = excl; excl += v2;
    cs[tid*4+3] = excl; cu[tid*4+3] = excl; excl += v3;
    if (tid == 1023) cs[NCELL] = excl;                // == NPTS
}

__global__ __launch_bounds__(256) void scatter_kernel(
    const float* __restrict__ xyz1, const float* __restrict__ xyz2,
    int* __restrict__ cursor, float4* __restrict__ spts)
{
    int t = blockIdx.x*256 + threadIdx.x;
    int s = t >> 14, i = t & (NPTS-1);
    const float* src = (s < 2 ? xyz1 : xyz2) + ((size_t)(s&1)*NPTS + i)*3;
    float x = src[0], y = src[1], z = src[2];
    int ix = clamp16((int)floorf((x-GLO)*GINVH));
    int iy = clamp16((int)floorf((y-GLO)*GINVH));
    int iz = clamp16((int)floorf((z-GLO)*GINVH));
    int code = mcode(ix,iy,iz);
    int pos = atomicAdd(&cursor[s*NCELL + code], 1);
    spts[s*NPTS + pos] = make_float4(x, y, z, __int_as_float(i));  // idx packed in .w
}

// ---- scheduling: heavy octets (dense home superblock) first ----
// Output perm[] only affects execution ORDER, never results.
__global__ __launch_bounds__(256) void sched_weight(
    const float4* __restrict__ spts, const int* __restrict__ cellStart,
    int* __restrict__ octbkt, int* __restrict__ bcnt)
{
    int o = blockIdx.x*256 + threadIdx.x;             // 0..8191, grid 32
    int set = o >> 11, dir = set >> 1, b = set & 1;
    int qset = (dir == 0) ? b : 2 + b;
    int cset = (dir == 0) ? 2 + b : b;
    int qbase = (o & 2047) << 3;
    float4 q = spts[qset*NPTS + qbase + 4];           // middle query of octet
    int sx = clamp16((int)floorf((q.x-GLO)*GINVH)) >> 1;
    int sy = clamp16((int)floorf((q.y-GLO)*GINVH)) >> 1;
    int sz = clamp16((int)floorf((q.z-GLO)*GINVH)) >> 1;
    int sb = spr3(sx) | (spr3(sy)<<1) | (spr3(sz)<<2);
    const int* cs = cellStart + cset*CS_STRIDE;
    int cnt = cs[(sb+1)<<3] - cs[sb<<3];              // home-superblock population
    int bkt = 31 - min(31, cnt >> 5);                 // bucket 0 = heaviest
    octbkt[o] = bkt;
    atomicAdd(&bcnt[bkt], 1);
}

__global__ __launch_bounds__(64) void sched_scan(
    const int* __restrict__ bcnt, int* __restrict__ bcur)
{
    if (threadIdx.x == 0) {
        int acc = 0;
        for (int k = 0; k < 32; ++k) { bcur[k] = acc; acc += bcnt[k]; }
    }
}

__global__ __launch_bounds__(256) void sched_scatter(
    const int* __restrict__ octbkt, int* __restrict__ bcur, int* __restrict__ perm)
{
    int o = blockIdx.x*256 + threadIdx.x;             // grid 32
    int pos = atomicAdd(&bcur[octbkt[o]], 1);
    perm[pos] = o;
}

// 8 lanes per query, 8 queries per wave; wave processes octet perm[slot]
// (heavy-first schedule). Internals identical to the r16 champion:
// superblock Morton-contiguous scan, stride-8, 4x-unrolled, 1 load/eval
// (idx in .w, bsq recomputed with EXACT rn chain), cs[] on scalar pipe.
// Exact key (r2/r5): t=fma(az,cz,fma(ay,cy,ax*cx)); d=fma(-2,t,rn(asq+bsq)).
// Lex-min (d, orig_idx) == np.argmin first-occurrence; conservative prune
// 0.995*LB - 3e-4; order-independent.
__global__ __launch_bounds__(256) void nn_kernel(
    const float4* __restrict__ spts,
    const int* __restrict__ cellStart, const int* __restrict__ perm,
    float* __restrict__ out)
{
    const int gt   = blockIdx.x*256 + threadIdx.x;
    const int lane = gt & 63;
    const int slot = gt >> 6;                 // 0..8191 launch slot
    const int wv   = __builtin_amdgcn_readfirstlane(perm[slot]);
    const int set  = wv >> 11;                // 0..3 = dir*2 + b
    const int dir  = set >> 1;
    const int b    = set & 1;
    const int qset = (dir == 0) ? b : 2 + b;
    const int cset = (dir == 0) ? 2 + b : b;
    const int qbase = (wv & 2047) << 3;       // 8 queries per wave
    const int qsub  = lane >> 3;              // 0..7: which query
    const int sub   = lane & 7;               // 0..7: candidate split
    const int qpos  = qbase + qsub;

    float4 q = spts[qset*NPTS + qpos];
    const int qorig = __float_as_int(q.w);
    const float ax = q.x, ay = q.y, az = q.z;
    const float aw = __fadd_rn(__fadd_rn(__fmul_rn(ax,ax), __fmul_rn(ay,ay)), __fmul_rn(az,az));

    int ix = clamp16((int)floorf((ax-GLO)*GINVH));
    int iy = clamp16((int)floorf((ay-GLO)*GINVH));
    int iz = clamp16((int)floorf((az-GLO)*GINVH));

    // wave cell bounding box (8 distinct queries, duplicated x8)
    int bx0 = ix, bx1 = ix, by0 = iy, by1 = iy, bz0 = iz, bz1 = iz;
    #pragma unroll
    for (int m = 32; m; m >>= 1) {
        bx0 = min(bx0, __shfl_xor(bx0, m, 64)); bx1 = max(bx1, __shfl_xor(bx1, m, 64));
        by0 = min(by0, __shfl_xor(by0, m, 64)); by1 = max(by1, __shfl_xor(by1, m, 64));
        bz0 = min(bz0, __shfl_xor(bz0, m, 64)); bz1 = max(bz1, __shfl_xor(bz1, m, 64));
    }
    const int sx0 = __builtin_amdgcn_readfirstlane(bx0 >> 1);
    const int sx1 = __builtin_amdgcn_readfirstlane(bx1 >> 1);
    const int sy0 = __builtin_amdgcn_readfirstlane(by0 >> 1);
    const int sy1 = __builtin_amdgcn_readfirstlane(by1 >> 1);
    const int sz0 = __builtin_amdgcn_readfirstlane(bz0 >> 1);
    const int sz1 = __builtin_amdgcn_readfirstlane(bz1 >> 1);

    const float4* cp = spts + cset*NPTS;
    const int*    cs = cellStart + cset*CS_STRIDE;

    float bd = __builtin_inff(); int bi = 0;

    #define EVAL(c4)                                                             \
    {                                                                            \
        float bsq = __fadd_rn(__fadd_rn(__fmul_rn((c4).x,(c4).x),                \
                                        __fmul_rn((c4).y,(c4).y)),               \
                              __fmul_rn((c4).z,(c4).z));                         \
        float tt = fmaf(az, (c4).z, fmaf(ay, (c4).y, __fmul_rn(ax, (c4).x)));    \
        float dd = fmaf(-2.0f, tt, __fadd_rn(aw, bsq));                          \
        int cix = __float_as_int((c4).w);                                        \
        bool bet = (dd < bd) || (dd == bd && cix < bi);                          \
        bd = bet ? dd : bd; bi = bet ? cix : bi;                                 \
    }

    #define SCAN_RANGE(j0, j1)                                                   \
    {                                                                            \
        int j = (j0) + sub;                                                      \
        for (; j + 24 < (j1); j += 32) {                                         \
            float4 c0 = cp[j];                                                   \
            float4 c1 = cp[j+8];                                                 \
            float4 c2 = cp[j+16];                                                \
            float4 c3 = cp[j+24];                                                \
            EVAL(c0); EVAL(c1); EVAL(c2); EVAL(c3);                              \
        }                                                                        \
        for (; j < (j1); j += 8) {                                               \
            float4 c4 = cp[j];                                                   \
            EVAL(c4);                                                            \
        }                                                                        \
    }

    // seed window around the wave's sorted position (Morton locality)
    {
        int s0 = qbase + 4 - 80; if (s0 < 0) s0 = 0;
        int e0 = s0 + 160;       if (e0 > NPTS) { e0 = NPTS; s0 = e0 - 160; }
        s0 = __builtin_amdgcn_readfirstlane(s0);
        e0 = __builtin_amdgcn_readfirstlane(e0);
        SCAN_RANGE(s0, e0);
    }

    // superblock (2x2x2 cells, width 1.0) Chebyshev shells outward
    for (int s = 0; s <= 8; ++s) {
        int zlo = max(0, sz0 - s), zhi = min(SGRID-1, sz1 + s);
        int ylo = max(0, sy0 - s), yhi = min(SGRID-1, sy1 + s);
        int xlo = max(0, sx0 - s), xhi = min(SGRID-1, sx1 + s);
        for (int scz = zlo; scz <= zhi; ++scz) {
            int cdz = max(0, max(sz0 - scz, scz - sz1));
            float lo = (scz == 0)       ? -1e30f : (GLO + (float)(scz*2    )*GH);
            float hi = (scz == SGRID-1) ?  1e30f : (GLO + (float)(scz*2 + 2)*GH);
            float dzz = fmaxf(0.0f, fmaxf(lo - az, az - hi));
            float dz2 = __fmul_rn(dzz, dzz);
            for (int scy = ylo; scy <= yhi; ++scy) {
                int cdy = max(cdz, max(0, max(sy0 - scy, scy - sy1)));
                if (cdy > s) continue;
                lo = (scy == 0)       ? -1e30f : (GLO + (float)(scy*2    )*GH);
                hi = (scy == SGRID-1) ?  1e30f : (GLO + (float)(scy*2 + 2)*GH);
                float dyy = fmaxf(0.0f, fmaxf(lo - ay, ay - hi));
                float dyz2 = fmaf(dyy, dyy, dz2);
                int sbyz = (spr3(scy)<<1) | (spr3(scz)<<2);
                for (int scx = xlo; scx <= xhi; ++scx) {
                    int cd = max(cdy, max(0, max(sx0 - scx, scx - sx1)));
                    if (cd != s) continue;
                    lo = (scx == 0)       ? -1e30f : (GLO + (float)(scx*2    )*GH);
                    hi = (scx == SGRID-1) ?  1e30f : (GLO + (float)(scx*2 + 2)*GH);
                    float dxx = fmaxf(0.0f, fmaxf(lo - ax, ax - hi));
                    float lb = fmaf(dxx, dxx, dyz2);
                    if (__ballot(fmaf(0.995f, lb, -3e-4f) <= bd) == 0ULL) continue;
                    int sb = spr3(scx) | sbyz;
                    int j0 = __builtin_amdgcn_readfirstlane(cs[sb<<3]);
                    int j1 = __builtin_amdgcn_readfirstlane(cs[(sb+1)<<3]);
                    SCAN_RANGE(j0, j1);
                }
            }
        }
        float wmax = bd;
        #pragma unroll
        for (int m = 32; m; m >>= 1) wmax = fmaxf(wmax, __shfl_xor(wmax, m, 64));
        float rs = (float)s;                  // unvisited: Euclid >= s * 1.0
        if (fmaf(0.995f, rs*rs, -3e-4f) > wmax) break;
        if (xlo == 0 && ylo == 0 && zlo == 0 &&
            xhi == SGRID-1 && yhi == SGRID-1 && zhi == SGRID-1) break; // grid covered
    }

    #undef SCAN_RANGE
    #undef EVAL

    // reduce the 8 sub-lanes of each query: lex-min (d, orig_idx)
    #pragma unroll
    for (int m = 1; m < 8; m <<= 1) {
        float od = __shfl_xor(bd, m, 64);
        int   oi = __shfl_xor(bi, m, 64);
        bool bet = (od < bd) || (od == bd && oi < bi);
        bd = bet ? od : bd; bi = bet ? oi : bi;
    }

    if (sub == 0) {
        int off  = dir ? 32768 : 0;
        int slot2 = b*NPTS + qorig;
        out[off + slot2]         = bd;
        out[65536 + off + slot2] = (float)bi;
    }
}

// fallback (no/small ws): brute force, exact chain
__global__ __launch_bounds__(256) void nn_full(
    const float* __restrict__ xyz1, const float* __restrict__ xyz2,
    float* __restrict__ out)
{
    int qid = blockIdx.x*256 + threadIdx.x;
    int dir = qid >> 15;
    int q15 = qid & 32767;
    const float* qsrc = dir ? xyz2 : xyz1;
    float ax = qsrc[q15*3+0], ay = qsrc[q15*3+1], az = qsrc[q15*3+2];
    float asq = __fadd_rn(__fadd_rn(__fmul_rn(ax,ax), __fmul_rn(ay,ay)), __fmul_rn(az,az));
    const float* cp = (dir ? xyz1 : xyz2) + (size_t)(q15 & NPTS)*3;
    float bd = 3.402823466e+38f; int bi = 0;
    for (int j = 0; j < NPTS; ++j) {
        float bx = cp[3*j+0], by = cp[3*j+1], bz = cp[3*j+2];
        float bsq = __fadd_rn(__fadd_rn(__fmul_rn(bx,bx), __fmul_rn(by,by)), __fmul_rn(bz,bz));
        float tt = fmaf(az, bz, fmaf(ay, by, __fmul_rn(ax, bx)));
        float d = fmaf(-2.0f, tt, __fadd_rn(asq, bsq));
        if (d < bd) { bd = d; bi = j; }
    }
    int off = dir ? 32768 : 0;
    out[off + q15]         = bd;
    out[65536 + off + q15] = (float)bi;
}

extern "C" void kernel_launch(void* const* d_in, const int* in_sizes, int n_in,
                              void* d_out, int out_size, void* d_ws, size_t ws_size,
                              hipStream_t stream) {
    const float* xyz1 = (const float*)d_in[0];
    const float* xyz2 = (const float*)d_in[1];
    float* out = (float*)d_out;

    const size_t off_spts = 0;
    const size_t off_cs   = 1048576;
    const size_t off_hist = 1114128;
    const size_t off_cur  = 1179664;
    const size_t off_bkt  = 1245200;
    const size_t off_bcnt = 1277968;
    const size_t off_bcur = 1278096;
    const size_t off_perm = 1278224;
    const size_t need     = 1310992;

    if (d_ws != nullptr && ws_size >= need) {
        float4* spts = (float4*)((char*)d_ws + off_spts);
        int* cstart  = (int*)((char*)d_ws + off_cs);
        int* hist    = (int*)((char*)d_ws + off_hist);
        int* cursor  = (int*)((char*)d_ws + off_cur);
        int* octbkt  = (int*)((char*)d_ws + off_bkt);
        int* bcnt    = (int*)((char*)d_ws + off_bcnt);
        int* bcur    = (int*)((char*)d_ws + off_bcur);
        int* perm    = (int*)((char*)d_ws + off_perm);
        zero_hist    <<<64,  256, 0, stream>>>(hist, bcnt, bcur);
        bin_kernel   <<<256, 256, 0, stream>>>(xyz1, xyz2, hist);
        scan_kernel  <<<4,  1024, 0, stream>>>(hist, cstart, cursor);
        scatter_kernel<<<256,256, 0, stream>>>(xyz1, xyz2, cursor, spts);
        sched_weight <<<32,  256, 0, stream>>>(spts, cstart, octbkt, bcnt);
        sched_scan   <<<1,    64, 0, stream>>>(bcnt, bcur);
        sched_scatter<<<32,  256, 0, stream>>>(octbkt, bcur, perm);
        nn_kernel    <<<2048,256, 0, stream>>>(spts, cstart, perm, out);
    } else {
        nn_full<<<65536/256, 256, 0, stream>>>(xyz1, xyz2, out);
    }
}

// Round 19
// 193.116 us; speedup vs baseline: 1.5235x; 1.5235x over previous
//
#include <hip/hip_runtime.h>

#define NPTS 16384
#define GRID 16
#define SGRID 8
#define NCELL 4096          // 16^3
#define CS_STRIDE (NCELL+1)
#define GLO -4.0f
#define GH 0.5f
#define GINVH 2.0f
#define NQTOT 65536

// sets: 0 = xyz1[b=0], 1 = xyz1[b=1], 2 = xyz2[b=0], 3 = xyz2[b=1]
// ws layout (bytes):
//   float4 spts[4][NPTS]            @ 0        (1048576)  Morton-sorted; w = __int_as_float(orig idx)
//   int    cellStart[4][NCELL+1]    @ 1048576  (65552)
//   int    hist[4][NCELL]           @ 1114128  (65536)
//   int    cursor[4][NCELL]         @ 1179664  (65536)
//   float  pd[2][NQTOT]             @ 1245200  (524288)   per-half partial min
//   int    pi[2][NQTOT]             @ 1769488  (524288)   per-half partial argmin
// total 2293776 bytes

__device__ __forceinline__ int clamp16(int v){ return v<0?0:(v>15?15:v); }
__device__ __forceinline__ int spr3(int v){           // 4-bit -> bits 0,3,6,9
    return (v&1) | ((v&2)<<2) | ((v&4)<<4) | ((v&8)<<6);
}
__device__ __forceinline__ int mcode(int ix,int iy,int iz){
    return spr3(ix) | (spr3(iy)<<1) | (spr3(iz)<<2);  // 12-bit Morton
}

__global__ __launch_bounds__(256) void zero_hist(int* __restrict__ hist){
    hist[blockIdx.x*256 + threadIdx.x] = 0;           // grid 64 -> 16384 ints
}

__global__ __launch_bounds__(256) void bin_kernel(
    const float* __restrict__ xyz1, const float* __restrict__ xyz2,
    int* __restrict__ hist)
{
    int t = blockIdx.x*256 + threadIdx.x;             // 0..65535
    int s = t >> 14, i = t & (NPTS-1);
    const float* src = (s < 2 ? xyz1 : xyz2) + ((size_t)(s&1)*NPTS + i)*3;
    float x = src[0], y = src[1], z = src[2];
    int ix = clamp16((int)floorf((x-GLO)*GINVH));
    int iy = clamp16((int)floorf((y-GLO)*GINVH));
    int iz = clamp16((int)floorf((z-GLO)*GINVH));
    atomicAdd(&hist[s*NCELL + mcode(ix,iy,iz)], 1);
}

// one block (1024 thr) per set: exclusive scan of 4096 counts
__global__ __launch_bounds__(1024) void scan_kernel(
    const int* __restrict__ hist, int* __restrict__ cellStart, int* __restrict__ cursor)
{
    int s = blockIdx.x, tid = threadIdx.x, lane = tid & 63, w = tid >> 6; // 16 waves
    const int* h = hist + s*NCELL;
    int v0 = h[tid*4+0], v1 = h[tid*4+1], v2 = h[tid*4+2], v3 = h[tid*4+3];
    int tsum = v0+v1+v2+v3;
    int x = tsum;
    #pragma unroll
    for (int d = 1; d < 64; d <<= 1) { int y = __shfl_up(x, d, 64); if (lane >= d) x += y; }
    __shared__ int wsum[16];
    if (lane == 63) wsum[w] = x;
    __syncthreads();
    if (tid == 0) { int acc = 0; for (int i2 = 0; i2 < 16; ++i2) { int tt = wsum[i2]; wsum[i2] = acc; acc += tt; } }
    __syncthreads();
    int excl = x - tsum + wsum[w];
    int* cs = cellStart + s*CS_STRIDE;
    int* cu = cursor   + s*NCELL;
    cs[tid*4+0] = excl; cu[tid*4+0] = excl; excl += v0;
    cs[tid*4+1] = excl; cu[tid*4+1] = excl; excl += v1;
    cs[tid*4+2] = excl; cu[tid*4+2] = excl; excl += v2;
    cs[tid*4+3] = excl; cu[tid*4+3] = excl; excl += v3;
    if (tid == 1023) cs[NCELL] = excl;                // == NPTS
}

__global__ __launch_bounds__(256) void scatter_kernel(
    const float* __restrict__ xyz1, const float* __restrict__ xyz2,
    int* __restrict__ cursor, float4* __restrict__ spts)
{
    int t = blockIdx.x*256 + threadIdx.x;
    int s = t >> 14, i = t & (NPTS-1);
    const float* src = (s < 2 ? xyz1 : xyz2) + ((size_t)(s&1)*NPTS + i)*3;
    float x = src[0], y = src[1], z = src[2];
    int ix = clamp16((int)floorf((x-GLO)*GINVH));
    int iy = clamp16((int)floorf((y-GLO)*GINVH));
    int iz = clamp16((int)floorf((z-GLO)*GINVH));
    int code = mcode(ix,iy,iz);
    int pos = atomicAdd(&cursor[s*NCELL + code], 1);
    spts[s*NPTS + pos] = make_float4(x, y, z, __int_as_float(i));  // idx packed in .w
}

// Wave = (octet, half): 8 queries/wave, candidate ranges scanned at stride 16
// (csplit = sub + half*8). Each half-wave computes partial lex-min over its
// half of every range and writes pd/pi[half][qid]; merge_kernel combines.
// Straggler critical path halves; static slot order (octet*2+half) keeps
// Morton locality (r18 lesson). Half-local bd >= true min -> ballot prune &
// termination stay conservative. Internals otherwise = r16 champion:
// 1 load/eval (idx in .w, bsq recomputed, EXACT rn chain), cs[] scalar pipe.
// Exact key (r2/r5): t=fma(az,cz,fma(ay,cy,ax*cx)); d=fma(-2,t,rn(asq+bsq)).
// Disjoint halves + lex-(d,orig_idx) merge == np.argmin first-occurrence.
__global__ __launch_bounds__(256) void nn_kernel(
    const float4* __restrict__ spts,
    const int* __restrict__ cellStart,
    float* __restrict__ pd, int* __restrict__ pi)
{
    const int gt   = blockIdx.x*256 + threadIdx.x;
    const int lane = gt & 63;
    const int slot = gt >> 6;                 // 0..16383
    const int wv   = slot >> 1;               // octet 0..8191
    const int half = slot & 1;
    const int set  = wv >> 11;                // 0..3 = dir*2 + b
    const int dir  = set >> 1;
    const int b    = set & 1;
    const int qset = (dir == 0) ? b : 2 + b;
    const int cset = (dir == 0) ? 2 + b : b;
    const int qbase = (wv & 2047) << 3;       // 8 queries per octet
    const int qsub  = lane >> 3;              // 0..7: which query
    const int sub   = lane & 7;
    const int csplit = sub + (half << 3);     // 0..15: candidate split
    const int qpos  = qbase + qsub;

    float4 q = spts[qset*NPTS + qpos];
    const int qorig = __float_as_int(q.w);
    const float ax = q.x, ay = q.y, az = q.z;
    const float aw = __fadd_rn(__fadd_rn(__fmul_rn(ax,ax), __fmul_rn(ay,ay)), __fmul_rn(az,az));

    int ix = clamp16((int)floorf((ax-GLO)*GINVH));
    int iy = clamp16((int)floorf((ay-GLO)*GINVH));
    int iz = clamp16((int)floorf((az-GLO)*GINVH));

    // wave cell bounding box (8 distinct queries, duplicated x8)
    int bx0 = ix, bx1 = ix, by0 = iy, by1 = iy, bz0 = iz, bz1 = iz;
    #pragma unroll
    for (int m = 32; m; m >>= 1) {
        bx0 = min(bx0, __shfl_xor(bx0, m, 64)); bx1 = max(bx1, __shfl_xor(bx1, m, 64));
        by0 = min(by0, __shfl_xor(by0, m, 64)); by1 = max(by1, __shfl_xor(by1, m, 64));
        bz0 = min(bz0, __shfl_xor(bz0, m, 64)); bz1 = max(bz1, __shfl_xor(bz1, m, 64));
    }
    const int sx0 = __builtin_amdgcn_readfirstlane(bx0 >> 1);
    const int sx1 = __builtin_amdgcn_readfirstlane(bx1 >> 1);
    const int sy0 = __builtin_amdgcn_readfirstlane(by0 >> 1);
    const int sy1 = __builtin_amdgcn_readfirstlane(by1 >> 1);
    const int sz0 = __builtin_amdgcn_readfirstlane(bz0 >> 1);
    const int sz1 = __builtin_amdgcn_readfirstlane(bz1 >> 1);

    const float4* cp = spts + cset*NPTS;
    const int*    cs = cellStart + cset*CS_STRIDE;

    float bd = __builtin_inff(); int bi = 0;

    #define EVAL(c4)                                                             \
    {                                                                            \
        float bsq = __fadd_rn(__fadd_rn(__fmul_rn((c4).x,(c4).x),                \
                                        __fmul_rn((c4).y,(c4).y)),               \
                              __fmul_rn((c4).z,(c4).z));                         \
        float tt = fmaf(az, (c4).z, fmaf(ay, (c4).y, __fmul_rn(ax, (c4).x)));    \
        float dd = fmaf(-2.0f, tt, __fadd_rn(aw, bsq));                          \
        int cix = __float_as_int((c4).w);                                        \
        bool bet = (dd < bd) || (dd == bd && cix < bi);                          \
        bd = bet ? dd : bd; bi = bet ? cix : bi;                                 \
    }

    // stride-16 scan of [j0,j1), 4x unrolled batched loads for MLP
    #define SCAN_RANGE(j0, j1)                                                   \
    {                                                                            \
        int j = (j0) + csplit;                                                   \
        for (; j + 48 < (j1); j += 64) {                                         \
            float4 c0 = cp[j];                                                   \
            float4 c1 = cp[j+16];                                                \
            float4 c2 = cp[j+32];                                                \
            float4 c3 = cp[j+48];                                                \
            EVAL(c0); EVAL(c1); EVAL(c2); EVAL(c3);                              \
        }                                                                        \
        for (; j < (j1); j += 16) {                                              \
            float4 c4 = cp[j];                                                   \
            EVAL(c4);                                                            \
        }                                                                        \
    }

    // seed window around the wave's sorted position (Morton locality)
    {
        int s0 = qbase + 4 - 80; if (s0 < 0) s0 = 0;
        int e0 = s0 + 160;       if (e0 > NPTS) { e0 = NPTS; s0 = e0 - 160; }
        s0 = __builtin_amdgcn_readfirstlane(s0);
        e0 = __builtin_amdgcn_readfirstlane(e0);
        SCAN_RANGE(s0, e0);
    }

    // superblock (2x2x2 cells, width 1.0) Chebyshev shells outward
    for (int s = 0; s <= 8; ++s) {
        int zlo = max(0, sz0 - s), zhi = min(SGRID-1, sz1 + s);
        int ylo = max(0, sy0 - s), yhi = min(SGRID-1, sy1 + s);
        int xlo = max(0, sx0 - s), xhi = min(SGRID-1, sx1 + s);
        for (int scz = zlo; scz <= zhi; ++scz) {
            int cdz = max(0, max(sz0 - scz, scz - sz1));
            float lo = (scz == 0)       ? -1e30f : (GLO + (float)(scz*2    )*GH);
            float hi = (scz == SGRID-1) ?  1e30f : (GLO + (float)(scz*2 + 2)*GH);
            float dzz = fmaxf(0.0f, fmaxf(lo - az, az - hi));
            float dz2 = __fmul_rn(dzz, dzz);
            for (int scy = ylo; scy <= yhi; ++scy) {
                int cdy = max(cdz, max(0, max(sy0 - scy, scy - sy1)));
                if (cdy > s) continue;
                lo = (scy == 0)       ? -1e30f : (GLO + (float)(scy*2    )*GH);
                hi = (scy == SGRID-1) ?  1e30f : (GLO + (float)(scy*2 + 2)*GH);
                float dyy = fmaxf(0.0f, fmaxf(lo - ay, ay - hi));
                float dyz2 = fmaf(dyy, dyy, dz2);
                int sbyz = (spr3(scy)<<1) | (spr3(scz)<<2);
                for (int scx = xlo; scx <= xhi; ++scx) {
                    int cd = max(cdy, max(0, max(sx0 - scx, scx - sx1)));
                    if (cd != s) continue;
                    lo = (scx == 0)       ? -1e30f : (GLO + (float)(scx*2    )*GH);
                    hi = (scx == SGRID-1) ?  1e30f : (GLO + (float)(scx*2 + 2)*GH);
                    float dxx = fmaxf(0.0f, fmaxf(lo - ax, ax - hi));
                    float lb = fmaf(dxx, dxx, dyz2);
                    if (__ballot(fmaf(0.995f, lb, -3e-4f) <= bd) == 0ULL) continue;
                    int sb = spr3(scx) | sbyz;
                    int j0 = __builtin_amdgcn_readfirstlane(cs[sb<<3]);
                    int j1 = __builtin_amdgcn_readfirstlane(cs[(sb+1)<<3]);
                    SCAN_RANGE(j0, j1);
                }
            }
        }
        float wmax = bd;
        #pragma unroll
        for (int m = 32; m; m >>= 1) wmax = fmaxf(wmax, __shfl_xor(wmax, m, 64));
        float rs = (float)s;                  // unvisited: Euclid >= s * 1.0
        if (fmaf(0.995f, rs*rs, -3e-4f) > wmax) break;
        if (xlo == 0 && ylo == 0 && zlo == 0 &&
            xhi == SGRID-1 && yhi == SGRID-1 && zhi == SGRID-1) break; // grid covered
    }

    #undef SCAN_RANGE
    #undef EVAL

    // reduce the 8 sub-lanes of this half: lex-min (d, orig_idx)
    #pragma unroll
    for (int m = 1; m < 8; m <<= 1) {
        float od = __shfl_xor(bd, m, 64);
        int   oi = __shfl_xor(bi, m, 64);
        bool bet = (od < bd) || (od == bd && oi < bi);
        bd = bet ? od : bd; bi = bet ? oi : bi;
    }

    if (sub == 0) {
        int qid = (dir << 15) + b*NPTS + qorig;    // 0..65535
        pd[half*NQTOT + qid] = bd;
        pi[half*NQTOT + qid] = bi;
    }
}

__global__ __launch_bounds__(256) void merge_kernel(
    const float* __restrict__ pd, const int* __restrict__ pi,
    float* __restrict__ out)
{
    int qid = blockIdx.x*256 + threadIdx.x;          // 0..65535
    float d0 = pd[qid];          int i0 = pi[qid];
    float d1 = pd[NQTOT + qid];  int i1 = pi[NQTOT + qid];
    bool bet = (d1 < d0) || (d1 == d0 && i1 < i0);   // lower index wins ties
    float bd = bet ? d1 : d0;
    int   bi = bet ? i1 : i0;
    out[qid]         = bd;       // [dist1|dist2] = qid 0..65535
    out[NQTOT + qid] = (float)bi;
}

// fallback (no/small ws): brute force, exact chain
__global__ __launch_bounds__(256) void nn_full(
    const float* __restrict__ xyz1, const float* __restrict__ xyz2,
    float* __restrict__ out)
{
    int qid = blockIdx.x*256 + threadIdx.x;
    int dir = qid >> 15;
    int q15 = qid & 32767;
    const float* qsrc = dir ? xyz2 : xyz1;
    float ax = qsrc[q15*3+0], ay = qsrc[q15*3+1], az = qsrc[q15*3+2];
    float asq = __fadd_rn(__fadd_rn(__fmul_rn(ax,ax), __fmul_rn(ay,ay)), __fmul_rn(az,az));
    const float* cp = (dir ? xyz1 : xyz2) + (size_t)(q15 & NPTS)*3;
    float bd = 3.402823466e+38f; int bi = 0;
    for (int j = 0; j < NPTS; ++j) {
        float bx = cp[3*j+0], by = cp[3*j+1], bz = cp[3*j+2];
        float bsq = __fadd_rn(__fadd_rn(__fmul_rn(bx,bx), __fmul_rn(by,by)), __fmul_rn(bz,bz));
        float tt = fmaf(az, bz, fmaf(ay, by, __fmul_rn(ax, bx)));
        float d = fmaf(-2.0f, tt, __fadd_rn(asq, bsq));
        if (d < bd) { bd = d; bi = j; }
    }
    int off = dir ? 32768 : 0;
    out[off + q15]         = bd;
    out[65536 + off + q15] = (float)bi;
}

extern "C" void kernel_launch(void* const* d_in, const int* in_sizes, int n_in,
                              void* d_out, int out_size, void* d_ws, size_t ws_size,
                              hipStream_t stream) {
    const float* xyz1 = (const float*)d_in[0];
    const float* xyz2 = (const float*)d_in[1];
    float* out = (float*)d_out;

    const size_t off_spts = 0;
    const size_t off_cs   = 1048576;
    const size_t off_hist = 1114128;
    const size_t off_cur  = 1179664;
    const size_t off_pd   = 1245200;
    const size_t off_pi   = 1769488;
    const size_t need     = 2293776;

    if (d_ws != nullptr && ws_size >= need) {
        float4* spts = (float4*)((char*)d_ws + off_spts);
        int* cstart  = (int*)((char*)d_ws + off_cs);
        int* hist    = (int*)((char*)d_ws + off_hist);
        int* cursor  = (int*)((char*)d_ws + off_cur);
        float* pd    = (float*)((char*)d_ws + off_pd);
        int*   pi    = (int*)((char*)d_ws + off_pi);
        zero_hist   <<<64,  256, 0, stream>>>(hist);
        bin_kernel  <<<256, 256, 0, stream>>>(xyz1, xyz2, hist);
        scan_kernel <<<4,  1024, 0, stream>>>(hist, cstart, cursor);
        scatter_kernel<<<256,256,0, stream>>>(xyz1, xyz2, cursor, spts);
        nn_kernel   <<<4096, 256, 0, stream>>>(spts, cstart, pd, pi);
        merge_kernel<<<256,  256, 0, stream>>>(pd, pi, out);
    } else {
        nn_full<<<65536/256, 256, 0, stream>>>(xyz1, xyz2, out);
    }
}

// Round 20
// 177.098 us; speedup vs baseline: 1.6613x; 1.0904x over previous
//
#include <hip/hip_runtime.h>

#define NPTS 16384
#define GRID 16
#define SGRID 8
#define NCELL 4096          // 16^3
#define CS_STRIDE (NCELL+1)
#define GLO -4.0f
#define GH 0.5f
#define GINVH 2.0f

// sets: 0 = xyz1[b=0], 1 = xyz1[b=1], 2 = xyz2[b=0], 3 = xyz2[b=1]
// ws layout (bytes):
//   float4 spts[4][NPTS]            @ 0        (1048576)  Morton-sorted; w = __int_as_float(orig idx)
//   int    cellStart[4][NCELL+1]    @ 1048576  (65552)
//   int    hist[4][NCELL]           @ 1114128  (65536)
//   int    cursor[4][NCELL]         @ 1179664  (65536)
// total 1245200 bytes

__device__ __forceinline__ int clamp16(int v){ return v<0?0:(v>15?15:v); }
__device__ __forceinline__ int spr3(int v){           // 4-bit -> bits 0,3,6,9
    return (v&1) | ((v&2)<<2) | ((v&4)<<4) | ((v&8)<<6);
}
__device__ __forceinline__ int mcode(int ix,int iy,int iz){
    return spr3(ix) | (spr3(iy)<<1) | (spr3(iz)<<2);  // 12-bit Morton
}

__global__ __launch_bounds__(256) void zero_hist(int* __restrict__ hist){
    hist[blockIdx.x*256 + threadIdx.x] = 0;           // grid 64 -> 16384 ints
}

__global__ __launch_bounds__(256) void bin_kernel(
    const float* __restrict__ xyz1, const float* __restrict__ xyz2,
    int* __restrict__ hist)
{
    int t = blockIdx.x*256 + threadIdx.x;             // 0..65535
    int s = t >> 14, i = t & (NPTS-1);
    const float* src = (s < 2 ? xyz1 : xyz2) + ((size_t)(s&1)*NPTS + i)*3;
    float x = src[0], y = src[1], z = src[2];
    int ix = clamp16((int)floorf((x-GLO)*GINVH));
    int iy = clamp16((int)floorf((y-GLO)*GINVH));
    int iz = clamp16((int)floorf((z-GLO)*GINVH));
    atomicAdd(&hist[s*NCELL + mcode(ix,iy,iz)], 1);
}

// one block (1024 thr) per set: exclusive scan of 4096 counts
__global__ __launch_bounds__(1024) void scan_kernel(
    const int* __restrict__ hist, int* __restrict__ cellStart, int* __restrict__ cursor)
{
    int s = blockIdx.x, tid = threadIdx.x, lane = tid & 63, w = tid >> 6; // 16 waves
    const int* h = hist + s*NCELL;
    int v0 = h[tid*4+0], v1 = h[tid*4+1], v2 = h[tid*4+2], v3 = h[tid*4+3];
    int tsum = v0+v1+v2+v3;
    int x = tsum;
    #pragma unroll
    for (int d = 1; d < 64; d <<= 1) { int y = __shfl_up(x, d, 64); if (lane >= d) x += y; }
    __shared__ int wsum[16];
    if (lane == 63) wsum[w] = x;
    __syncthreads();
    if (tid == 0) { int acc = 0; for (int i2 = 0; i2 < 16; ++i2) { int tt = wsum[i2]; wsum[i2] = acc; acc += tt; } }
    __syncthreads();
    int excl = x - tsum + wsum[w];
    int* cs = cellStart + s*CS_STRIDE;
    int* cu = cursor   + s*NCELL;
    cs[tid*4+0] = excl; cu[tid*4+0] = excl; excl += v0;
    cs[tid*4+1] = excl; cu[tid*4+1] = excl; excl += v1;
    cs[tid*4+2] = excl; cu[tid*4+2] = excl; excl += v2;
    cs[tid*4+3] = excl; cu[tid*4+3] = excl; excl += v3;
    if (tid == 1023) cs[NCELL] = excl;                // == NPTS
}

__global__ __launch_bounds__(256) void scatter_kernel(
    const float* __restrict__ xyz1, const float* __restrict__ xyz2,
    int* __restrict__ cursor, float4* __restrict__ spts)
{
    int t = blockIdx.x*256 + threadIdx.x;
    int s = t >> 14, i = t & (NPTS-1);
    const float* src = (s < 2 ? xyz1 : xyz2) + ((size_t)(s&1)*NPTS + i)*3;
    float x = src[0], y = src[1], z = src[2];
    int ix = clamp16((int)floorf((x-GLO)*GINVH));
    int iy = clamp16((int)floorf((y-GLO)*GINVH));
    int iz = clamp16((int)floorf((z-GLO)*GINVH));
    int code = mcode(ix,iy,iz);
    int pos = atomicAdd(&cursor[s*NCELL + code], 1);
    spts[s*NPTS + pos] = make_float4(x, y, z, __int_as_float(i));  // idx packed in .w
}

// r16 champion structure + EXACT seed-dedup: shell scans skip the sub-range
// already evaluated by the seed window ([s0g,e0g)) — identical key, lex-min is
// idempotent over duplicates, so results are provably unchanged.
// 8 lanes per query, 8 queries per wave, static octet per wave (8192 waves).
// Scan unit = SUPERBLOCK (Morton-contiguous), stride-8, 4x-unrolled, 1 load/eval
// (idx in .w, bsq recomputed with EXACT rn chain); cs[] wave-uniform -> scalar pipe.
// Exact key (r2/r5): t=fma(az,cz,fma(ay,cy,ax*cx)); d=fma(-2,t,rn(asq+bsq)).
// Lex-min (d, orig_idx) == np.argmin first-occurrence; conservative prune
// 0.995*LB - 3e-4; order-independent.
__global__ __launch_bounds__(256) void nn_kernel(
    const float4* __restrict__ spts,
    const int* __restrict__ cellStart, float* __restrict__ out)
{
    const int gt   = blockIdx.x*256 + threadIdx.x;
    const int lane = gt & 63;
    const int wv   = gt >> 6;                 // 0..8191
    const int set  = wv >> 11;                // 0..3 = dir*2 + b
    const int dir  = set >> 1;
    const int b    = set & 1;
    const int qset = (dir == 0) ? b : 2 + b;
    const int cset = (dir == 0) ? 2 + b : b;
    const int qbase = (wv & 2047) << 3;       // 8 queries per wave
    const int qsub  = lane >> 3;              // 0..7: which query
    const int sub   = lane & 7;               // 0..7: candidate split
    const int qpos  = qbase + qsub;

    float4 q = spts[qset*NPTS + qpos];
    const int qorig = __float_as_int(q.w);
    const float ax = q.x, ay = q.y, az = q.z;
    const float aw = __fadd_rn(__fadd_rn(__fmul_rn(ax,ax), __fmul_rn(ay,ay)), __fmul_rn(az,az));

    int ix = clamp16((int)floorf((ax-GLO)*GINVH));
    int iy = clamp16((int)floorf((ay-GLO)*GINVH));
    int iz = clamp16((int)floorf((az-GLO)*GINVH));

    // wave cell bounding box (8 distinct queries, duplicated x8)
    int bx0 = ix, bx1 = ix, by0 = iy, by1 = iy, bz0 = iz, bz1 = iz;
    #pragma unroll
    for (int m = 32; m; m >>= 1) {
        bx0 = min(bx0, __shfl_xor(bx0, m, 64)); bx1 = max(bx1, __shfl_xor(bx1, m, 64));
        by0 = min(by0, __shfl_xor(by0, m, 64)); by1 = max(by1, __shfl_xor(by1, m, 64));
        bz0 = min(bz0, __shfl_xor(bz0, m, 64)); bz1 = max(bz1, __shfl_xor(bz1, m, 64));
    }
    const int sx0 = __builtin_amdgcn_readfirstlane(bx0 >> 1);
    const int sx1 = __builtin_amdgcn_readfirstlane(bx1 >> 1);
    const int sy0 = __builtin_amdgcn_readfirstlane(by0 >> 1);
    const int sy1 = __builtin_amdgcn_readfirstlane(by1 >> 1);
    const int sz0 = __builtin_amdgcn_readfirstlane(bz0 >> 1);
    const int sz1 = __builtin_amdgcn_readfirstlane(bz1 >> 1);

    const float4* cp = spts + cset*NPTS;
    const int*    cs = cellStart + cset*CS_STRIDE;

    float bd = __builtin_inff(); int bi = 0;

    #define EVAL(c4)                                                             \
    {                                                                            \
        float bsq = __fadd_rn(__fadd_rn(__fmul_rn((c4).x,(c4).x),                \
                                        __fmul_rn((c4).y,(c4).y)),               \
                              __fmul_rn((c4).z,(c4).z));                         \
        float tt = fmaf(az, (c4).z, fmaf(ay, (c4).y, __fmul_rn(ax, (c4).x)));    \
        float dd = fmaf(-2.0f, tt, __fadd_rn(aw, bsq));                          \
        int cix = __float_as_int((c4).w);                                        \
        bool bet = (dd < bd) || (dd == bd && cix < bi);                          \
        bd = bet ? dd : bd; bi = bet ? cix : bi;                                 \
    }

    #define SCAN_RANGE(j0, j1)                                                   \
    {                                                                            \
        int j = (j0) + sub;                                                      \
        for (; j + 24 < (j1); j += 32) {                                         \
            float4 c0 = cp[j];                                                   \
            float4 c1 = cp[j+8];                                                 \
            float4 c2 = cp[j+16];                                                \
            float4 c3 = cp[j+24];                                                \
            EVAL(c0); EVAL(c1); EVAL(c2); EVAL(c3);                              \
        }                                                                        \
        for (; j < (j1); j += 8) {                                               \
            float4 c4 = cp[j];                                                   \
            EVAL(c4);                                                            \
        }                                                                        \
    }

    // scan [j0,j1) minus the already-evaluated seed window [s0g,e0g) — exact
    #define SCAN_CUT(j0, j1)                                                     \
    {                                                                            \
        int a1 = min((j1), s0g);                                                 \
        SCAN_RANGE((j0), a1);                                                    \
        int b0 = max((j0), e0g);                                                 \
        SCAN_RANGE(b0, (j1));                                                    \
    }

    // seed window around the wave's sorted position (Morton locality)
    int s0g, e0g;
    {
        int s0 = qbase + 4 - 80; if (s0 < 0) s0 = 0;
        int e0 = s0 + 160;       if (e0 > NPTS) { e0 = NPTS; s0 = e0 - 160; }
        s0g = __builtin_amdgcn_readfirstlane(s0);
        e0g = __builtin_amdgcn_readfirstlane(e0);
        SCAN_RANGE(s0g, e0g);
    }

    // superblock (2x2x2 cells, width 1.0) Chebyshev shells outward
    for (int s = 0; s <= 8; ++s) {
        int zlo = max(0, sz0 - s), zhi = min(SGRID-1, sz1 + s);
        int ylo = max(0, sy0 - s), yhi = min(SGRID-1, sy1 + s);
        int xlo = max(0, sx0 - s), xhi = min(SGRID-1, sx1 + s);
        for (int scz = zlo; scz <= zhi; ++scz) {
            int cdz = max(0, max(sz0 - scz, scz - sz1));
            float lo = (scz == 0)       ? -1e30f : (GLO + (float)(scz*2    )*GH);
            float hi = (scz == SGRID-1) ?  1e30f : (GLO + (float)(scz*2 + 2)*GH);
            float dzz = fmaxf(0.0f, fmaxf(lo - az, az - hi));
            float dz2 = __fmul_rn(dzz, dzz);
            for (int scy = ylo; scy <= yhi; ++scy) {
                int cdy = max(cdz, max(0, max(sy0 - scy, scy - sy1)));
                if (cdy > s) continue;
                lo = (scy == 0)       ? -1e30f : (GLO + (float)(scy*2    )*GH);
                hi = (scy == SGRID-1) ?  1e30f : (GLO + (float)(scy*2 + 2)*GH);
                float dyy = fmaxf(0.0f, fmaxf(lo - ay, ay - hi));
                float dyz2 = fmaf(dyy, dyy, dz2);
                int sbyz = (spr3(scy)<<1) | (spr3(scz)<<2);
                for (int scx = xlo; scx <= xhi; ++scx) {
                    int cd = max(cdy, max(0, max(sx0 - scx, scx - sx1)));
                    if (cd != s) continue;
                    lo = (scx == 0)       ? -1e30f : (GLO + (float)(scx*2    )*GH);
                    hi = (scx == SGRID-1) ?  1e30f : (GLO + (float)(scx*2 + 2)*GH);
                    float dxx = fmaxf(0.0f, fmaxf(lo - ax, ax - hi));
                    float lb = fmaf(dxx, dxx, dyz2);
                    if (__ballot(fmaf(0.995f, lb, -3e-4f) <= bd) == 0ULL) continue;
                    int sb = spr3(scx) | sbyz;
                    int j0 = __builtin_amdgcn_readfirstlane(cs[sb<<3]);
                    int j1 = __builtin_amdgcn_readfirstlane(cs[(sb+1)<<3]);
                    SCAN_CUT(j0, j1);
                }
            }
        }
        float wmax = bd;
        #pragma unroll
        for (int m = 32; m; m >>= 1) wmax = fmaxf(wmax, __shfl_xor(wmax, m, 64));
        float rs = (float)s;                  // unvisited: Euclid >= s * 1.0
        if (fmaf(0.995f, rs*rs, -3e-4f) > wmax) break;
        if (xlo == 0 && ylo == 0 && zlo == 0 &&
            xhi == SGRID-1 && yhi == SGRID-1 && zhi == SGRID-1) break; // grid covered
    }

    #undef SCAN_CUT
    #undef SCAN_RANGE
    #undef EVAL

    // reduce the 8 sub-lanes of each query: lex-min (d, orig_idx)
    #pragma unroll
    for (int m = 1; m < 8; m <<= 1) {
        float od = __shfl_xor(bd, m, 64);
        int   oi = __shfl_xor(bi, m, 64);
        bool bet = (od < bd) || (od == bd && oi < bi);
        bd = bet ? od : bd; bi = bet ? oi : bi;
    }

    if (sub == 0) {
        int off  = dir ? 32768 : 0;
        int slot = b*NPTS + qorig;
        out[off + slot]         = bd;
        out[65536 + off + slot] = (float)bi;
    }
}

// fallback (no/small ws): brute force, exact chain
__global__ __launch_bounds__(256) void nn_full(
    const float* __restrict__ xyz1, const float* __restrict__ xyz2,
    float* __restrict__ out)
{
    int qid = blockIdx.x*256 + threadIdx.x;
    int dir = qid >> 15;
    int q15 = qid & 32767;
    const float* qsrc = dir ? xyz2 : xyz1;
    float ax = qsrc[q15*3+0], ay = qsrc[q15*3+1], az = qsrc[q15*3+2];
    float asq = __fadd_rn(__fadd_rn(__fmul_rn(ax,ax), __fmul_rn(ay,ay)), __fmul_rn(az,az));
    const float* cp = (dir ? xyz1 : xyz2) + (size_t)(q15 & NPTS)*3;
    float bd = 3.402823466e+38f; int bi = 0;
    for (int j = 0; j < NPTS; ++j) {
        float bx = cp[3*j+0], by = cp[3*j+1], bz = cp[3*j+2];
        float bsq = __fadd_rn(__fadd_rn(__fmul_rn(bx,bx), __fmul_rn(by,by)), __fmul_rn(bz,bz));
        float tt = fmaf(az, bz, fmaf(ay, by, __fmul_rn(ax, bx)));
        float d = fmaf(-2.0f, tt, __fadd_rn(asq, bsq));
        if (d < bd) { bd = d; bi = j; }
    }
    int off = dir ? 32768 : 0;
    out[off + q15]         = bd;
    out[65536 + off + q15] = (float)bi;
}

extern "C" void kernel_launch(void* const* d_in, const int* in_sizes, int n_in,
                              void* d_out, int out_size, void* d_ws, size_t ws_size,
                              hipStream_t stream) {
    const float* xyz1 = (const float*)d_in[0];
    const float* xyz2 = (const float*)d_in[1];
    float* out = (float*)d_out;

    const size_t off_spts = 0;
    const size_t off_cs   = 1048576;
    const size_t off_hist = 1114128;
    const size_t off_cur  = 1179664;
    const size_t need     = 1245200;

    if (d_ws != nullptr && ws_size >= need) {
        float4* spts = (float4*)((char*)d_ws + off_spts);
        int* cstart  = (int*)((char*)d_ws + off_cs);
        int* hist    = (int*)((char*)d_ws + off_hist);
        int* cursor  = (int*)((char*)d_ws + off_cur);
        zero_hist   <<<64,  256, 0, stream>>>(hist);
        bin_kernel  <<<256, 256, 0, stream>>>(xyz1, xyz2, hist);
        scan_kernel <<<4,  1024, 0, stream>>>(hist, cstart, cursor);
        scatter_kernel<<<256,256,0, stream>>>(xyz1, xyz2, cursor, spts);
        nn_kernel   <<<2048, 256, 0, stream>>>(spts, cstart, out);
    } else {
        nn_full<<<65536/256, 256, 0, stream>>>(xyz1, xyz2, out);
    }
}